// Round 14
// baseline (274.089 us; speedup 1.0000x reference)
//
#include <hip/hip_runtime.h>
#include <hip/hip_bf16.h>

// MoChA. Round 14: (1) GEMM cores (proj + energy) use
// __builtin_amdgcn_global_load_lds width=16 (async global->LDS DMA, no VGPR
// round-trip; lane-contiguous unpadded LDS, ASTR=32); energy now LDS-staged
// too (was direct-global frags at 8% MfmaUtil). (2) e_chunk stored fp16.
// Alpha/beta/context structure unchanged from R13.
// B=8, Q=128, K=1024, D=512, HM=HC=4, CHUNK=4.

#define NEG_INF (-3.402823466e38f)
#define EPS_MOCHA 1e-6f
#define INV_SCALE 0.04419417382415922f  // 1/sqrt(512)

typedef _Float16 half8 __attribute__((ext_vector_type(8)));
typedef _Float16 half4v __attribute__((ext_vector_type(4)));
typedef float f32x4 __attribute__((ext_vector_type(4)));

// ---------------------------------------------------------------------------
// Wave64 inclusive add-scan via DPP: 6 VALU-latency steps.
// ---------------------------------------------------------------------------
__device__ __forceinline__ float wave_incl_scan(float x)
{
    int v;
    v = __builtin_amdgcn_update_dpp(0, __builtin_bit_cast(int, x), 0x111, 0xF, 0xF, false);
    x += __builtin_bit_cast(float, v);   // row_shr:1
    v = __builtin_amdgcn_update_dpp(0, __builtin_bit_cast(int, x), 0x112, 0xF, 0xF, false);
    x += __builtin_bit_cast(float, v);   // row_shr:2
    v = __builtin_amdgcn_update_dpp(0, __builtin_bit_cast(int, x), 0x114, 0xF, 0xF, false);
    x += __builtin_bit_cast(float, v);   // row_shr:4
    v = __builtin_amdgcn_update_dpp(0, __builtin_bit_cast(int, x), 0x118, 0xF, 0xF, false);
    x += __builtin_bit_cast(float, v);   // row_shr:8 -> row-inclusive
    v = __builtin_amdgcn_update_dpp(0, __builtin_bit_cast(int, x), 0x142, 0xA, 0xF, false);
    x += __builtin_bit_cast(float, v);   // row_bcast:15 -> rows 1,3
    v = __builtin_amdgcn_update_dpp(0, __builtin_bit_cast(int, x), 0x143, 0xC, 0xF, false);
    x += __builtin_bit_cast(float, v);   // row_bcast:31 -> rows 2,3
    return x;
}

// ---------------------------------------------------------------------------
// prep_kernel: one launch for all input packing.
// ---------------------------------------------------------------------------
__global__ __launch_bounds__(256) void prep_kernel(
    const float* __restrict__ key_x, const float* __restrict__ query_x,
    const float* __restrict__ wk_m, const float* __restrict__ wk_c,
    const float* __restrict__ wv, const float* __restrict__ wq_m,
    const float* __restrict__ wq_c, const float* __restrict__ wo,
    _Float16* __restrict__ K16, _Float16* __restrict__ Q16,
    _Float16* __restrict__ Wt5, _Float16* __restrict__ Wt_wo)
{
    __shared__ float T[64][65];
    const int bid = blockIdx.x;
    const int t = threadIdx.x;
    if (bid < 4608) {
        const float* in = (bid < 4096) ? key_x : query_x;
        _Float16* out = (bid < 4096) ? K16 : Q16;
        const size_t i = (size_t)(bid < 4096 ? bid : bid - 4096) * 256 + t;
        float4 v = *(const float4*)(in + i * 4);
        half4v h = {(_Float16)v.x, (_Float16)v.y, (_Float16)v.z, (_Float16)v.w};
        *(half4v*)(out + i * 4) = h;
        return;
    }
    const int idx = bid - 4608;
    const int z = idx >> 6, tile = idx & 63;
    const float* W = (z == 0) ? wk_m : (z == 1) ? wk_c : (z == 2) ? wv
                   : (z == 3) ? wq_m : (z == 4) ? wq_c : wo;
    _Float16* O = (z < 5) ? (Wt5 + (size_t)z * 262144) : Wt_wo;
    const int n0 = (tile & 7) * 64, k0 = (tile >> 3) * 64;
    const int rr = t >> 4, cc = (t & 15) * 4;
#pragma unroll
    for (int r = 0; r < 4; ++r) {
        int k = r * 16 + rr;
        float4 v = *(const float4*)(W + (size_t)(k0 + k) * 512 + n0 + cc);
        T[k][cc + 0] = v.x; T[k][cc + 1] = v.y;
        T[k][cc + 2] = v.z; T[k][cc + 3] = v.w;
    }
    __syncthreads();
    const int nn = t >> 2, kc = (t & 3) * 16;
    _Float16 tmp[16];
#pragma unroll
    for (int i = 0; i < 16; ++i) tmp[i] = (_Float16)T[kc + i][nn];
    _Float16* Op = O + (size_t)(n0 + nn) * 512 + k0 + kc;
    *(half8*)(Op)     = *(half8*)&tmp[0];
    *(half8*)(Op + 8) = *(half8*)&tmp[8];
}

__device__ __forceinline__ void mfma_step(half8 a[4], half8 b[4], f32x4 acc[4][4])
{
#pragma unroll
    for (int mt = 0; mt < 4; ++mt)
#pragma unroll
        for (int nt = 0; nt < 4; ++nt)
            acc[mt][nt] = __builtin_amdgcn_mfma_f32_16x16x32_f16(
                a[mt], b[nt], acc[mt][nt], 0, 0, 0);
}

// ---------------------------------------------------------------------------
// Async global->LDS 16B copy (wave-uniform base + lane*16 layout).
// ---------------------------------------------------------------------------
__device__ __forceinline__ void stage16(const _Float16* src, _Float16* dst)
{
    __builtin_amdgcn_global_load_lds(
        (const __attribute__((address_space(1))) void*)src,
        (__attribute__((address_space(3))) void*)dst, 16, 0, 0);
}

// ---------------------------------------------------------------------------
// LDS-staged MFMA accumulate core: 128x128 tile, BK=32, 2x2 waves.
// A/B rows are k-contiguous with stride 512; LDS unpadded (row = 32 halfs =
// 64B) so staging map (thread t -> LDS byte t*16) is lane-contiguous for
// global_load_lds. NSTEPS K-steps of 32.
// ---------------------------------------------------------------------------
template <int NSTEPS>
__device__ __forceinline__ void gemm_acc(
    const _Float16* __restrict__ Abase, const _Float16* __restrict__ Bbase,
    _Float16* As, _Float16* Bs, f32x4 acc[4][4])
{
    const int tid = threadIdx.x;
    const int lane = tid & 63, wave = tid >> 6;
    const int wm = wave >> 1, wn = wave & 1;
    const int col = lane & 15, quad = lane >> 4;
    const int r0 = tid >> 2, seg = tid & 3;

    const _Float16* Ag0 = Abase + (size_t)r0 * 512 + seg * 8;
    const _Float16* Ag1 = Ag0 + (size_t)64 * 512;
    const _Float16* Bg0 = Bbase + (size_t)r0 * 512 + seg * 8;
    const _Float16* Bg1 = Bg0 + (size_t)64 * 512;
    _Float16* Ad0 = As + tid * 8;
    _Float16* Ad1 = As + 2048 + tid * 8;
    _Float16* Bd0 = Bs + tid * 8;
    _Float16* Bd1 = Bs + 2048 + tid * 8;

    const _Float16* Afr = As + (size_t)(wm * 64 + col) * 32 + quad * 8;
    const _Float16* Bfr = Bs + (size_t)(wn * 64 + col) * 32 + quad * 8;

#pragma unroll
    for (int ks = 0; ks < NSTEPS; ++ks) {
        __syncthreads();  // prior consume done before overwrite
        stage16(Ag0 + ks * 32, Ad0);
        stage16(Ag1 + ks * 32, Ad1);
        stage16(Bg0 + ks * 32, Bd0);
        stage16(Bg1 + ks * 32, Bd1);
        __syncthreads();  // vmcnt(0) drain + barrier
        half8 a[4], b[4];
#pragma unroll
        for (int t = 0; t < 4; ++t) {
            a[t] = *(const half8*)(Afr + (size_t)t * 16 * 32);
            b[t] = *(const half8*)(Bfr + (size_t)t * 16 * 32);
        }
        mfma_step(a, b, acc);
    }
}

__device__ __forceinline__ void proj_epilogue(
    f32x4 acc[4][4], const float* __restrict__ bias, void* __restrict__ Cv,
    int m0, int n0, int f16o)
{
    const int tid = threadIdx.x;
    const int lane = tid & 63, wave = tid >> 6;
    const int wm = wave >> 1, wn = wave & 1;
    const int col = lane & 15, quad = lane >> 4;
    float bnt[4];
#pragma unroll
    for (int nt = 0; nt < 4; ++nt)
        bnt[nt] = bias[n0 + wn * 64 + nt * 16 + col];
#pragma unroll
    for (int mt = 0; mt < 4; ++mt) {
        const int rowb = m0 + wm * 64 + mt * 16 + quad * 4;
#pragma unroll
        for (int nt = 0; nt < 4; ++nt) {
            const int cc = n0 + wn * 64 + nt * 16 + col;
#pragma unroll
            for (int r = 0; r < 4; ++r) {
                float v = acc[mt][nt][r] + bnt[nt];
                if (f16o)
                    ((_Float16*)Cv)[(size_t)(rowb + r) * 512 + cc] = (_Float16)v;
                else
                    ((float*)Cv)[(size_t)(rowb + r) * 512 + cc] = v;
            }
        }
    }
}

// ---------------------------------------------------------------------------
// Merged key+query projection: 5 groups. g<3: A=K16 (M=8192); g>=3: A=Q16
// (M=1024, m-blocks 0..7). Grid: (64, 20). f16 outputs except V (g=2).
// ---------------------------------------------------------------------------
__global__ __launch_bounds__(256) void mfma_proj5(
    const _Float16* __restrict__ Akey, const _Float16* __restrict__ Aqry,
    const _Float16* __restrict__ Wt5,
    const float* __restrict__ b0, void* __restrict__ C0,
    const float* __restrict__ b1, void* __restrict__ C1,
    const float* __restrict__ b2, void* __restrict__ C2,
    const float* __restrict__ b3, void* __restrict__ C3,
    const float* __restrict__ b4, void* __restrict__ C4)
{
    __shared__ _Float16 As[4096];
    __shared__ _Float16 Bs[4096];
    const int g = blockIdx.y >> 2, nt128 = blockIdx.y & 3;
    const bool qry = g >= 3;
    if (qry && blockIdx.x >= 8) return;
    const _Float16* A16 = qry ? Aqry : Akey;
    const _Float16* Wt = Wt5 + (size_t)g * 262144;
    const float* bias = (g == 0) ? b0 : (g == 1) ? b1 : (g == 2) ? b2
                      : (g == 3) ? b3 : b4;
    void* Cv = (g == 0) ? C0 : (g == 1) ? C1 : (g == 2) ? C2
             : (g == 3) ? C3 : C4;
    const int f16o = (g == 2) ? 0 : 1;
    const int m0 = blockIdx.x * 128, n0 = nt128 * 128;

    f32x4 acc[4][4];
#pragma unroll
    for (int mt = 0; mt < 4; ++mt)
#pragma unroll
        for (int nt = 0; nt < 4; ++nt) acc[mt][nt] = (f32x4)0.f;
    gemm_acc<16>(A16 + (size_t)m0 * 512, Wt + (size_t)n0 * 512, As, Bs, acc);
    proj_epilogue(acc, bias, Cv, m0, n0, f16o);
}

// ---------------------------------------------------------------------------
// Output projection (M=1024, fp32 out). Grid: (8, 4).
// ---------------------------------------------------------------------------
__global__ __launch_bounds__(256) void mfma_proj_out(
    const _Float16* __restrict__ A16, const _Float16* __restrict__ Wt,
    const float* __restrict__ bias, float* __restrict__ C)
{
    __shared__ _Float16 As[4096];
    __shared__ _Float16 Bs[4096];
    const int m0 = blockIdx.x * 128, n0 = blockIdx.y * 128;
    f32x4 acc[4][4];
#pragma unroll
    for (int mt = 0; mt < 4; ++mt)
#pragma unroll
        for (int nt = 0; nt < 4; ++nt) acc[mt][nt] = (f32x4)0.f;
    gemm_acc<16>(A16 + (size_t)m0 * 512, Wt + (size_t)n0 * 512, As, Bs, acc);
    proj_epilogue(acc, bias, C, m0, n0, 0);
}

// ---------------------------------------------------------------------------
// Energy via LDS-staged MFMA, both heads in one launch (K=128, 4 steps).
// Grid: (kt=8, h=4, z=16); z<8: mono (b=z, +r, fp32 e_mono); z>=8: chunk
// (fp16 e_chunk16).
// ---------------------------------------------------------------------------
__global__ __launch_bounds__(256) void energy_mfma(
    const _Float16* __restrict__ Qm, const _Float16* __restrict__ Km,
    const _Float16* __restrict__ Qc, const _Float16* __restrict__ Kc,
    const int* __restrict__ mask, float* __restrict__ e_mono,
    _Float16* __restrict__ e_chunk16, const float* __restrict__ r_ptr)
{
    __shared__ _Float16 As[4096];
    __shared__ _Float16 Bs[4096];
    const int tid = threadIdx.x;
    const int lane = tid & 63, wave = tid >> 6;
    const int wm = wave >> 1, wn = wave & 1;
    const int col = lane & 15, quad = lane >> 4;
    const int kt0 = blockIdx.x * 128;
    const int h = blockIdx.y;
    const int z = blockIdx.z;
    const int b = z & 7;
    const bool mono = z < 8;
    const _Float16* Qp = mono ? Qm : Qc;
    const _Float16* Kp = mono ? Km : Kc;
    const float rv = mono ? r_ptr[0] : 0.f;

    f32x4 acc[4][4];
#pragma unroll
    for (int mt = 0; mt < 4; ++mt)
#pragma unroll
        for (int nt = 0; nt < 4; ++nt) acc[mt][nt] = (f32x4)0.f;
    gemm_acc<4>(Qp + (size_t)(b * 128) * 512 + h * 128,
                Kp + (size_t)(b * 1024 + kt0) * 512 + h * 128, As, Bs, acc);

#pragma unroll
    for (int mt = 0; mt < 4; ++mt) {
        const int qb = wm * 64 + mt * 16 + quad * 4;
#pragma unroll
        for (int nt = 0; nt < 4; ++nt) {
            const int kc = kt0 + wn * 64 + nt * 16 + col;
#pragma unroll
            for (int r = 0; r < 4; ++r) {
                const int q = qb + r;
                float v = acc[mt][nt][r] * INV_SCALE + rv;
                int mv = mask[((size_t)b * 128 + q) * 1024 + kc];
                v = mv ? v : NEG_INF;
                const size_t oi = (((size_t)b * 4 + h) * 128 + q) * 1024 + kc;
                if (mono) e_mono[oi] = v;
                else      e_chunk16[oi] = (_Float16)v;
            }
        }
    }
}

// ---------------------------------------------------------------------------
// transcend_row: (pcp, invcp) for one (b,h,q) row computed by one wave.
// ---------------------------------------------------------------------------
__device__ __forceinline__ void transcend_row(
    const float* __restrict__ Erow, int lane, float o_pcp[16], float o_inv[16])
{
    const float* E = Erow + lane * 16;
    float e[16];
    *(float4*)&e[0]  = *(const float4*)(E);
    *(float4*)&e[4]  = *(const float4*)(E + 4);
    *(float4*)&e[8]  = *(const float4*)(E + 8);
    *(float4*)&e[12] = *(const float4*)(E + 12);

    float p[16], l[16];
#pragma unroll
    for (int i = 0; i < 16; ++i) {
        p[i] = 1.f / (1.f + expf(-e[i]));
        l[i] = logf(fmaxf(1.f - p[i], EPS_MOCHA));
    }
    float incl[16];
    incl[0] = l[0];
#pragma unroll
    for (int i = 1; i < 16; ++i) incl[i] = incl[i - 1] + l[i];
    float total = incl[15];
    float x = wave_incl_scan(total);
    float base = x - total;  // exclusive across lanes
#pragma unroll
    for (int i = 0; i < 16; ++i) {
        float cl = base + (i ? incl[i - 1] : 0.f);
        float cp = expf(cl);
        o_pcp[i] = p[i] * cp;
        o_inv[i] = 1.f / fmaxf(cp, EPS_MOCHA);
    }
}

// ---------------------------------------------------------------------------
// alpha_pre: per row q (one wave, 4096 rows): pcp_q (stored) and
// G_q = pcp_{q-1} * invcp_q (G_0 = delta(k==0) * invcp_0[0]).
// ---------------------------------------------------------------------------
__global__ __launch_bounds__(256) void alpha_pre(
    const float* __restrict__ e_mono, float* __restrict__ G,
    float* __restrict__ pcp)
{
    const int tid = threadIdx.x;
    const int lane = tid & 63;
    const int row = blockIdx.x * 4 + (tid >> 6);
    const int q = row & 127;

    float pq[16], iq[16];
    transcend_row(e_mono + (size_t)row * 1024, lane, pq, iq);

    float* P = pcp + (size_t)row * 1024 + lane * 16;
    *(float4*)(P)      = *(float4*)&pq[0];
    *(float4*)(P + 4)  = *(float4*)&pq[4];
    *(float4*)(P + 8)  = *(float4*)&pq[8];
    *(float4*)(P + 12) = *(float4*)&pq[12];

    float g[16];
    if (q == 0) {
#pragma unroll
        for (int i = 0; i < 16; ++i) g[i] = 0.f;
        if (lane == 0) g[0] = iq[0];
    } else {
        float pm[16], im[16];
        transcend_row(e_mono + (size_t)(row - 1) * 1024, lane, pm, im);
#pragma unroll
        for (int i = 0; i < 16; ++i) g[i] = pm[i] * iq[i];
    }
    float* Gp = G + (size_t)row * 1024 + lane * 16;
    *(float4*)(Gp)      = *(float4*)&g[0];
    *(float4*)(Gp + 4)  = *(float4*)&g[4];
    *(float4*)(Gp + 8)  = *(float4*)&g[8];
    *(float4*)(Gp + 12) = *(float4*)&g[12];
}

// ---------------------------------------------------------------------------
// alpha_scan: one wave per (b,h), single 16MB stream (G), 8-deep prefetch,
// DPP wave scan. S_q = cumsum_k(G_q * S_{q-1}), S_{-1} = 1.
// ---------------------------------------------------------------------------
__global__ __launch_bounds__(64, 1) void alpha_scan(
    const float* __restrict__ G, float* __restrict__ S)
{
    const int lane = threadIdx.x;
    const int bh = blockIdx.x;
    const float* Gp = G + (size_t)bh * 131072 + lane * 16;
    float* Sp = S + (size_t)bh * 131072 + lane * 16;

    float bg[8][16];
#pragma unroll
    for (int s = 0; s < 8; ++s) {
        const float* Gq = Gp + (size_t)s * 1024;
        *(float4*)&bg[s][0]  = *(const float4*)(Gq);
        *(float4*)&bg[s][4]  = *(const float4*)(Gq + 4);
        *(float4*)&bg[s][8]  = *(const float4*)(Gq + 8);
        *(float4*)&bg[s][12] = *(const float4*)(Gq + 12);
    }

    float Sv[16];
#pragma unroll
    for (int i = 0; i < 16; ++i) Sv[i] = 1.f;  // S_{-1} = ones

    for (int q8 = 0; q8 < 128; q8 += 8) {
#pragma unroll
        for (int s = 0; s < 8; ++s) {
            const int q = q8 + s;
            float g[16];
#pragma unroll
            for (int i = 0; i < 16; ++i) g[i] = bg[s][i];
            if (q + 8 < 128) {  // refill slot s for q+8
                const float* Gq = Gp + (size_t)(q + 8) * 1024;
                *(float4*)&bg[s][0]  = *(const float4*)(Gq);
                *(float4*)&bg[s][4]  = *(const float4*)(Gq + 4);
                *(float4*)&bg[s][8]  = *(const float4*)(Gq + 8);
                *(float4*)&bg[s][12] = *(const float4*)(Gq + 12);
            }

            float incl[16];
            incl[0] = g[0] * Sv[0];
#pragma unroll
            for (int i = 1; i < 16; ++i)
                incl[i] = fmaf(g[i], Sv[i], incl[i - 1]);
            float total = incl[15];
            float x = wave_incl_scan(total);
            float base = x - total;
#pragma unroll
            for (int i = 0; i < 16; ++i) Sv[i] = base + incl[i];

            float* Sq = Sp + (size_t)q * 1024;
            *(float4*)(Sq)      = *(float4*)&Sv[0];
            *(float4*)(Sq + 4)  = *(float4*)&Sv[4];
            *(float4*)(Sq + 8)  = *(float4*)&Sv[8];
            *(float4*)(Sq + 12) = *(float4*)&Sv[12];
        }
    }
}

// ---------------------------------------------------------------------------
// Beta -> fp16. One block per (b,q); alpha = pcp*S reconstructed on load;
// e_chunk read as fp16. LDS swizzle SW(k)=k+(k>>3). Grid: (q=128, b=8).
// ---------------------------------------------------------------------------
#define SW(k) ((k) + ((k) >> 3))

__global__ __launch_bounds__(256) void beta_kernel(
    const _Float16* __restrict__ e_chunk16, const float* __restrict__ pcp,
    const float* __restrict__ S, _Float16* __restrict__ beta)
{
    __shared__ float sm[SW(1023) + 1];
    __shared__ float tm[SW(1027) + 1];
    __shared__ float red[4];
    const int q = blockIdx.x, b = blockIdx.y;
    const int tid = threadIdx.x;
    const int lane = tid & 63, wid = tid >> 6;
    const int k4 = tid * 4;

    float av[4][4];
#pragma unroll
    for (int hm = 0; hm < 4; ++hm) {
        const size_t off = (((size_t)b * 4 + hm) * 128 + q) * 1024 + k4;
        float4 pv = *(const float4*)(pcp + off);
        float4 sv = *(const float4*)(S + off);
        av[hm][0] = pv.x * sv.x;
        av[hm][1] = pv.y * sv.y;
        av[hm][2] = pv.z * sv.z;
        av[hm][3] = pv.w * sv.w;
    }

    if (tid < 4) tm[SW(1024 + tid)] = 0.f;  // fwd-window zero pad (set once)

    for (int hc = 0; hc < 4; ++hc) {
        half4v ev = *(const half4v*)(e_chunk16 + (((size_t)b * 4 + hc) * 128 + q) * 1024 + k4);
        float e[4] = {(float)ev[0], (float)ev[1], (float)ev[2], (float)ev[3]};

        float mx = fmaxf(fmaxf(e[0], e[1]), fmaxf(e[2], e[3]));
#pragma unroll
        for (int off = 32; off >= 1; off >>= 1)
            mx = fmaxf(mx, __shfl_xor(mx, off, 64));
        if (lane == 0) red[wid] = mx;
        __syncthreads();
        mx = fmaxf(fmaxf(red[0], red[1]), fmaxf(red[2], red[3]));

        float sx[4];
#pragma unroll
        for (int i = 0; i < 4; ++i) {
            sx[i] = fmaxf(expf(e[i] - mx), 1e-5f);
            sm[SW(k4 + i)] = sx[i];
        }
        __syncthreads();

        float den[4];
#pragma unroll
        for (int i = 0; i < 4; ++i) {
            int k = k4 + i;
            float d = sm[SW(k)];
            if (k >= 1) d += sm[SW(k - 1)];
            if (k >= 2) d += sm[SW(k - 2)];
            if (k >= 3) d += sm[SW(k - 3)];
            den[i] = d;
        }

#pragma unroll
        for (int hm = 0; hm < 4; ++hm) {
            float t[4] = {av[hm][0] / den[0], av[hm][1] / den[1],
                          av[hm][2] / den[2], av[hm][3] / den[3]};
#pragma unroll
            for (int i = 0; i < 4; ++i) tm[SW(k4 + i)] = t[i];
            __syncthreads();
            float o[4];
#pragma unroll
            for (int i = 0; i < 4; ++i) {
                int k = k4 + i;
                float ms = tm[SW(k)] + tm[SW(k + 1)] + tm[SW(k + 2)] + tm[SW(k + 3)];
                o[i] = sx[i] * ms;
            }
            _Float16* Brow = beta + (((size_t)b * 16 + hm * 4 + hc) * 128 + q) * 1024;
            half4v hv = {(_Float16)o[0], (_Float16)o[1], (_Float16)o[2], (_Float16)o[3]};
            *(half4v*)(Brow + k4) = hv;
            __syncthreads();
        }
    }
}

// ---------------------------------------------------------------------------
// Context: cv16[b,q,h*32+d] = (fp16) sum_k beta16[b,h,q,k] * V[b,k,h*32+d]
// ---------------------------------------------------------------------------
__global__ __launch_bounds__(256) void context_kernel(
    const _Float16* __restrict__ beta, const float* __restrict__ V,
    _Float16* __restrict__ cv16)
{
    __shared__ float bS[32][64];
    __shared__ float vS[32][32];
    const int qh = blockIdx.x, h = blockIdx.y, b = blockIdx.z;
    const int tid = threadIdx.x;
    const int ty = tid >> 3, tx = tid & 7;
    const int q0 = qh * 64;

    const _Float16* Bbase = beta + (((size_t)b * 16 + h) * 128 + q0) * 1024;
    const float* Vbase = V + (size_t)b * 1024 * 512 + h * 32;

    float acc[2][4];
#pragma unroll
    for (int i = 0; i < 2; ++i)
#pragma unroll
        for (int j = 0; j < 4; ++j) acc[i][j] = 0.f;

    for (int k0 = 0; k0 < 1024; k0 += 32) {
        {
            int r = tid >> 2, c = tid & 3;
            half8 v = *(const half8*)(Bbase + (size_t)r * 1024 + k0 + c * 8);
#pragma unroll
            for (int j = 0; j < 8; ++j) bS[c * 8 + j][r] = (float)v[j];
        }
        {
            int kk = tid >> 3, c = tid & 7;
            float4 v = *(const float4*)(Vbase + (size_t)(k0 + kk) * 512 + c * 4);
            *(float4*)&vS[kk][c * 4] = v;
        }
        __syncthreads();
#pragma unroll
        for (int kk = 0; kk < 32; ++kk) {
            float a0 = bS[kk][ty * 2], a1 = bS[kk][ty * 2 + 1];
            float bb[4];
            *(float4*)bb = *(const float4*)&vS[kk][tx * 4];
#pragma unroll
            for (int j = 0; j < 4; ++j) {
                acc[0][j] = fmaf(a0, bb[j], acc[0][j]);
                acc[1][j] = fmaf(a1, bb[j], acc[1][j]);
            }
        }
        __syncthreads();
    }
#pragma unroll
    for (int i = 0; i < 2; ++i) {
        _Float16* Cp = cv16 + ((size_t)b * 128 + q0 + ty * 2 + i) * 512 + h * 32 + tx * 4;
        half4v hv = {(_Float16)acc[i][0], (_Float16)acc[i][1],
                     (_Float16)acc[i][2], (_Float16)acc[i][3]};
        *(half4v*)Cp = hv;
    }
}

// ---------------------------------------------------------------------------
extern "C" void kernel_launch(void* const* d_in, const int* in_sizes, int n_in,
                              void* d_out, int out_size, void* d_ws, size_t ws_size,
                              hipStream_t stream)
{
    const float* key_x   = (const float*)d_in[0];
    const float* query_x = (const float*)d_in[1];
    const int*   mask    = (const int*)d_in[2];
    const float* wk_m = (const float*)d_in[3];
    const float* bk_m = (const float*)d_in[4];
    const float* wq_m = (const float*)d_in[5];
    const float* bq_m = (const float*)d_in[6];
    const float* r    = (const float*)d_in[7];
    const float* wk_c = (const float*)d_in[8];
    const float* bk_c = (const float*)d_in[9];
    const float* wq_c = (const float*)d_in[10];
    const float* bq_c = (const float*)d_in[11];
    const float* wv   = (const float*)d_in[12];
    const float* bv   = (const float*)d_in[13];
    const float* wo   = (const float*)d_in[14];
    const float* bo   = (const float*)d_in[15];
    float* out = (float*)d_out;

    float* ws = (float*)d_ws;
    _Float16* hws = (_Float16*)d_ws;
    const size_t MEGF = 1024 * 1024;
    // Float-unit layout (fp16 offsets are 2x float offsets):
    //  phase A: K16 f[0,2), Q16 f[4,4.25), Wt5 f[4.5,5.25),
    //           Km16 f[6,8), Kc16 f[8,10), Qm16 f[10,10.125),
    //           Qc16 f[10.25,10.375), e_mono f[11,15), e_chunk16 f[15,17),
    //           V f[19,23), Wt_wo f[27.5,27.625)
    //  phase B (alpha): G f[0,4); pcp f[8,10) (dead Kc16); S f[23,27)
    //  phase C: beta16 f[0,8) (G/Km16 etc. dead; pcp preserved),
    //           cv16 f[27.75,28). Peak 28 MEGF.
    _Float16* K16   = hws;                          // f 0
    _Float16* Q16   = hws + 8 * MEGF;               // f 4
    _Float16* Wt5   = hws + 9 * MEGF;               // f 4.5
    _Float16* Km16  = hws + 12 * MEGF;              // f 6
    _Float16* Kc16  = hws + 16 * MEGF;              // f 8
    _Float16* Qm16  = hws + 20 * MEGF;              // f 10
    _Float16* Qc16  = hws + 20 * MEGF + MEGF / 2;   // f 10.25
    float* e_mono  = ws + 11 * MEGF;
    _Float16* e_chunk16 = hws + 30 * MEGF;          // f 15
    float* V       = ws + 19 * MEGF;
    float* G       = ws;                            // f 0 (over dead K16)
    float* pcp     = ws + 8 * MEGF;                 // f 8 (over dead Kc16)
    float* S       = ws + 23 * MEGF;                // f 23
    _Float16* beta16 = hws;                         // f 0 (phase C overlay)
    _Float16* Wt_wo = hws + 55 * MEGF;              // f 27.5
    _Float16* cv16  = hws + 55 * MEGF + MEGF / 2;   // f 27.75

    // 0) merged prep: cvt key/query + pack 6 weights
    prep_kernel<<<dim3(4992), 256, 0, stream>>>(
        key_x, query_x, wk_m, wk_c, wv, wq_m, wq_c, wo,
        K16, Q16, Wt5, Wt_wo);
    // 1) all five projections in one launch (async-LDS GEMM)
    mfma_proj5<<<dim3(64, 20), 256, 0, stream>>>(
        K16, Q16, Wt5,
        bk_m, Km16, bk_c, Kc16, bv, V, bq_m, Qm16, bq_c, Qc16);
    // 2) both energies in one launch (async-LDS GEMM; chunk head -> fp16)
    energy_mfma<<<dim3(8, 4, 16), 256, 0, stream>>>(
        Qm16, Km16, Qc16, Kc16, mask, e_mono, e_chunk16, r);
    // 3) monotonic alpha: G/pcp precompute + single-stream DPP scan
    alpha_pre<<<dim3(1024), 256, 0, stream>>>(e_mono, G, pcp);
    alpha_scan<<<dim3(32), 64, 0, stream>>>(G, S);
    // 4) chunkwise beta (fp16 out), one block per (b,q); aw = pcp*S inline
    beta_kernel<<<dim3(128, 8), 256, 0, stream>>>(e_chunk16, pcp, S, beta16);
    // 5) context vectors -> cv16 directly
    context_kernel<<<dim3(2, 16, 8), 256, 0, stream>>>(beta16, V, cv16);
    // 6) output projection (M=1024, fp32 out)
    mfma_proj_out<<<dim3(8, 4), 256, 0, stream>>>(cv16, Wt_wo, bo, out);
}

// Round 15
// 270.809 us; speedup vs baseline: 1.0121x; 1.0121x over previous
//
#include <hip/hip_runtime.h>
#include <hip/hip_bf16.h>

// MoChA. Round 15: (1) activation fp32->fp16 cvt fused into proj5 A-staging
// (K16/Q16 buffers and their prep work eliminated; prep packs weights only);
// (2) workspace layout re-audited — fixes latent pcp/e_mono overlap race
// (R13/R14 passed by dispatch-order luck). 7 dispatches.
// B=8, Q=128, K=1024, D=512, HM=HC=4, CHUNK=4.

#define NEG_INF (-3.402823466e38f)
#define EPS_MOCHA 1e-6f
#define INV_SCALE 0.04419417382415922f  // 1/sqrt(512)

typedef _Float16 half8 __attribute__((ext_vector_type(8)));
typedef _Float16 half4v __attribute__((ext_vector_type(4)));
typedef float f32x4 __attribute__((ext_vector_type(4)));

// ---------------------------------------------------------------------------
// Wave64 inclusive add-scan via DPP: 6 VALU-latency steps.
// ---------------------------------------------------------------------------
__device__ __forceinline__ float wave_incl_scan(float x)
{
    int v;
    v = __builtin_amdgcn_update_dpp(0, __builtin_bit_cast(int, x), 0x111, 0xF, 0xF, false);
    x += __builtin_bit_cast(float, v);   // row_shr:1
    v = __builtin_amdgcn_update_dpp(0, __builtin_bit_cast(int, x), 0x112, 0xF, 0xF, false);
    x += __builtin_bit_cast(float, v);   // row_shr:2
    v = __builtin_amdgcn_update_dpp(0, __builtin_bit_cast(int, x), 0x114, 0xF, 0xF, false);
    x += __builtin_bit_cast(float, v);   // row_shr:4
    v = __builtin_amdgcn_update_dpp(0, __builtin_bit_cast(int, x), 0x118, 0xF, 0xF, false);
    x += __builtin_bit_cast(float, v);   // row_shr:8 -> row-inclusive
    v = __builtin_amdgcn_update_dpp(0, __builtin_bit_cast(int, x), 0x142, 0xA, 0xF, false);
    x += __builtin_bit_cast(float, v);   // row_bcast:15 -> rows 1,3
    v = __builtin_amdgcn_update_dpp(0, __builtin_bit_cast(int, x), 0x143, 0xC, 0xF, false);
    x += __builtin_bit_cast(float, v);   // row_bcast:31 -> rows 2,3
    return x;
}

// ---------------------------------------------------------------------------
// prep_weights: transpose-pack 6 weights to Wt[n][k] fp16. Grid: (8,8,6).
// ---------------------------------------------------------------------------
__global__ __launch_bounds__(256) void prep_weights(
    const float* __restrict__ wk_m, const float* __restrict__ wk_c,
    const float* __restrict__ wv, const float* __restrict__ wq_m,
    const float* __restrict__ wq_c, const float* __restrict__ wo,
    _Float16* __restrict__ Wt5, _Float16* __restrict__ Wt_wo)
{
    __shared__ float T[64][65];
    const int z = blockIdx.z;
    const float* W = (z == 0) ? wk_m : (z == 1) ? wk_c : (z == 2) ? wv
                   : (z == 3) ? wq_m : (z == 4) ? wq_c : wo;
    _Float16* O = (z < 5) ? (Wt5 + (size_t)z * 262144) : Wt_wo;
    const int n0 = blockIdx.x * 64, k0 = blockIdx.y * 64;
    const int t = threadIdx.x;
    const int rr = t >> 4, cc = (t & 15) * 4;
#pragma unroll
    for (int r = 0; r < 4; ++r) {
        int k = r * 16 + rr;
        float4 v = *(const float4*)(W + (size_t)(k0 + k) * 512 + n0 + cc);
        T[k][cc + 0] = v.x; T[k][cc + 1] = v.y;
        T[k][cc + 2] = v.z; T[k][cc + 3] = v.w;
    }
    __syncthreads();
    const int nn = t >> 2, kc = (t & 3) * 16;
    _Float16 tmp[16];
#pragma unroll
    for (int i = 0; i < 16; ++i) tmp[i] = (_Float16)T[kc + i][nn];
    _Float16* Op = O + (size_t)(n0 + nn) * 512 + k0 + kc;
    *(half8*)(Op)     = *(half8*)&tmp[0];
    *(half8*)(Op + 8) = *(half8*)&tmp[8];
}

__device__ __forceinline__ void mfma_step(half8 a[4], half8 b[4], f32x4 acc[4][4])
{
#pragma unroll
    for (int mt = 0; mt < 4; ++mt)
#pragma unroll
        for (int nt = 0; nt < 4; ++nt)
            acc[mt][nt] = __builtin_amdgcn_mfma_f32_16x16x32_f16(
                a[mt], b[nt], acc[mt][nt], 0, 0, 0);
}

// ---------------------------------------------------------------------------
// Async global->LDS 16B copy (wave-uniform base + lane*16 layout).
// ---------------------------------------------------------------------------
__device__ __forceinline__ void stage16(const _Float16* src, _Float16* dst)
{
    __builtin_amdgcn_global_load_lds(
        (const __attribute__((address_space(1))) void*)src,
        (__attribute__((address_space(3))) void*)dst, 16, 0, 0);
}

__device__ __forceinline__ half8 cvt8(float4 a, float4 b)
{
    half8 h = {(_Float16)a.x, (_Float16)a.y, (_Float16)a.z, (_Float16)a.w,
               (_Float16)b.x, (_Float16)b.y, (_Float16)b.z, (_Float16)b.w};
    return h;
}

// ---------------------------------------------------------------------------
// GEMM core, A in fp32 (cvt fused into staging, 1-deep register prefetch
// overlapping MFMA); B fp16 via async global_load_lds. 128x128 tile, BK=32,
// 2x2 waves, NSTEPS K-steps. LDS unpadded (row = 32 halfs).
// ---------------------------------------------------------------------------
template <int NSTEPS>
__device__ __forceinline__ void gemm_acc_af32(
    const float* __restrict__ Abase, const _Float16* __restrict__ Bbase,
    _Float16* As, _Float16* Bs, f32x4 acc[4][4])
{
    const int tid = threadIdx.x;
    const int lane = tid & 63, wave = tid >> 6;
    const int wm = wave >> 1, wn = wave & 1;
    const int col = lane & 15, quad = lane >> 4;
    const int r0 = tid >> 2, seg = tid & 3;

    const float* Af0 = Abase + (size_t)r0 * 512 + seg * 8;
    const float* Af1 = Af0 + (size_t)64 * 512;
    const _Float16* Bg0 = Bbase + (size_t)r0 * 512 + seg * 8;
    const _Float16* Bg1 = Bg0 + (size_t)64 * 512;
    _Float16* Ad0 = As + tid * 8;
    _Float16* Ad1 = As + 2048 + tid * 8;
    _Float16* Bd0 = Bs + tid * 8;
    _Float16* Bd1 = Bs + 2048 + tid * 8;

    const _Float16* Afr = As + (size_t)(wm * 64 + col) * 32 + quad * 8;
    const _Float16* Bfr = Bs + (size_t)(wn * 64 + col) * 32 + quad * 8;

    float4 fa0, fa1, fb0, fb1;  // A fp32 prefetch regs (rows r0, r0+64)
    fa0 = *(const float4*)(Af0);
    fa1 = *(const float4*)(Af0 + 4);
    fb0 = *(const float4*)(Af1);
    fb1 = *(const float4*)(Af1 + 4);

#pragma unroll
    for (int ks = 0; ks < NSTEPS; ++ks) {
        __syncthreads();  // prior consume done before overwrite
        *(half8*)Ad0 = cvt8(fa0, fa1);
        *(half8*)Ad1 = cvt8(fb0, fb1);
        stage16(Bg0 + ks * 32, Bd0);
        stage16(Bg1 + ks * 32, Bd1);
        __syncthreads();  // drains vmcnt + lgkm
        if (ks + 1 < NSTEPS) {  // prefetch next A tile; overlaps MFMA below
            const int k0 = (ks + 1) * 32;
            fa0 = *(const float4*)(Af0 + k0);
            fa1 = *(const float4*)(Af0 + k0 + 4);
            fb0 = *(const float4*)(Af1 + k0);
            fb1 = *(const float4*)(Af1 + k0 + 4);
        }
        half8 a[4], b[4];
#pragma unroll
        for (int t = 0; t < 4; ++t) {
            a[t] = *(const half8*)(Afr + (size_t)t * 16 * 32);
            b[t] = *(const half8*)(Bfr + (size_t)t * 16 * 32);
        }
        mfma_step(a, b, acc);
    }
}

// ---------------------------------------------------------------------------
// GEMM core, both operands fp16 via async global_load_lds (R14 behavior).
// ---------------------------------------------------------------------------
template <int NSTEPS>
__device__ __forceinline__ void gemm_acc_f16(
    const _Float16* __restrict__ Abase, const _Float16* __restrict__ Bbase,
    _Float16* As, _Float16* Bs, f32x4 acc[4][4])
{
    const int tid = threadIdx.x;
    const int lane = tid & 63, wave = tid >> 6;
    const int wm = wave >> 1, wn = wave & 1;
    const int col = lane & 15, quad = lane >> 4;
    const int r0 = tid >> 2, seg = tid & 3;

    const _Float16* Ag0 = Abase + (size_t)r0 * 512 + seg * 8;
    const _Float16* Ag1 = Ag0 + (size_t)64 * 512;
    const _Float16* Bg0 = Bbase + (size_t)r0 * 512 + seg * 8;
    const _Float16* Bg1 = Bg0 + (size_t)64 * 512;
    _Float16* Ad0 = As + tid * 8;
    _Float16* Ad1 = As + 2048 + tid * 8;
    _Float16* Bd0 = Bs + tid * 8;
    _Float16* Bd1 = Bs + 2048 + tid * 8;

    const _Float16* Afr = As + (size_t)(wm * 64 + col) * 32 + quad * 8;
    const _Float16* Bfr = Bs + (size_t)(wn * 64 + col) * 32 + quad * 8;

#pragma unroll
    for (int ks = 0; ks < NSTEPS; ++ks) {
        __syncthreads();
        stage16(Ag0 + ks * 32, Ad0);
        stage16(Ag1 + ks * 32, Ad1);
        stage16(Bg0 + ks * 32, Bd0);
        stage16(Bg1 + ks * 32, Bd1);
        __syncthreads();
        half8 a[4], b[4];
#pragma unroll
        for (int t = 0; t < 4; ++t) {
            a[t] = *(const half8*)(Afr + (size_t)t * 16 * 32);
            b[t] = *(const half8*)(Bfr + (size_t)t * 16 * 32);
        }
        mfma_step(a, b, acc);
    }
}

__device__ __forceinline__ void proj_epilogue(
    f32x4 acc[4][4], const float* __restrict__ bias, void* __restrict__ Cv,
    int m0, int n0, int f16o)
{
    const int tid = threadIdx.x;
    const int lane = tid & 63, wave = tid >> 6;
    const int wm = wave >> 1, wn = wave & 1;
    const int col = lane & 15, quad = lane >> 4;
    float bnt[4];
#pragma unroll
    for (int nt = 0; nt < 4; ++nt)
        bnt[nt] = bias[n0 + wn * 64 + nt * 16 + col];
#pragma unroll
    for (int mt = 0; mt < 4; ++mt) {
        const int rowb = m0 + wm * 64 + mt * 16 + quad * 4;
#pragma unroll
        for (int nt = 0; nt < 4; ++nt) {
            const int cc = n0 + wn * 64 + nt * 16 + col;
#pragma unroll
            for (int r = 0; r < 4; ++r) {
                float v = acc[mt][nt][r] + bnt[nt];
                if (f16o)
                    ((_Float16*)Cv)[(size_t)(rowb + r) * 512 + cc] = (_Float16)v;
                else
                    ((float*)Cv)[(size_t)(rowb + r) * 512 + cc] = v;
            }
        }
    }
}

// ---------------------------------------------------------------------------
// Merged key+query projection from fp32 activations. 5 groups:
// g<3: A=key_x (M=8192); g>=3: A=query_x (M=1024, m-blocks 0..7).
// Grid: (64, 20). f16 outputs except V (g=2).
// ---------------------------------------------------------------------------
__global__ __launch_bounds__(256) void mfma_proj5(
    const float* __restrict__ key_x, const float* __restrict__ query_x,
    const _Float16* __restrict__ Wt5,
    const float* __restrict__ b0, void* __restrict__ C0,
    const float* __restrict__ b1, void* __restrict__ C1,
    const float* __restrict__ b2, void* __restrict__ C2,
    const float* __restrict__ b3, void* __restrict__ C3,
    const float* __restrict__ b4, void* __restrict__ C4)
{
    __shared__ _Float16 As[4096];
    __shared__ _Float16 Bs[4096];
    const int g = blockIdx.y >> 2, nt128 = blockIdx.y & 3;
    const bool qry = g >= 3;
    if (qry && blockIdx.x >= 8) return;
    const float* A = qry ? query_x : key_x;
    const _Float16* Wt = Wt5 + (size_t)g * 262144;
    const float* bias = (g == 0) ? b0 : (g == 1) ? b1 : (g == 2) ? b2
                      : (g == 3) ? b3 : b4;
    void* Cv = (g == 0) ? C0 : (g == 1) ? C1 : (g == 2) ? C2
             : (g == 3) ? C3 : C4;
    const int f16o = (g == 2) ? 0 : 1;
    const int m0 = blockIdx.x * 128, n0 = nt128 * 128;

    f32x4 acc[4][4];
#pragma unroll
    for (int mt = 0; mt < 4; ++mt)
#pragma unroll
        for (int nt = 0; nt < 4; ++nt) acc[mt][nt] = (f32x4)0.f;
    gemm_acc_af32<16>(A + (size_t)m0 * 512, Wt + (size_t)n0 * 512, As, Bs, acc);
    proj_epilogue(acc, bias, Cv, m0, n0, f16o);
}

// ---------------------------------------------------------------------------
// Output projection (A = cv16 fp16, M=1024, fp32 out). Grid: (8, 4).
// ---------------------------------------------------------------------------
__global__ __launch_bounds__(256) void mfma_proj_out(
    const _Float16* __restrict__ A16, const _Float16* __restrict__ Wt,
    const float* __restrict__ bias, float* __restrict__ C)
{
    __shared__ _Float16 As[4096];
    __shared__ _Float16 Bs[4096];
    const int m0 = blockIdx.x * 128, n0 = blockIdx.y * 128;
    f32x4 acc[4][4];
#pragma unroll
    for (int mt = 0; mt < 4; ++mt)
#pragma unroll
        for (int nt = 0; nt < 4; ++nt) acc[mt][nt] = (f32x4)0.f;
    gemm_acc_f16<16>(A16 + (size_t)m0 * 512, Wt + (size_t)n0 * 512, As, Bs, acc);
    proj_epilogue(acc, bias, C, m0, n0, 0);
}

// ---------------------------------------------------------------------------
// Energy via LDS-staged MFMA, both heads in one launch (K=128, 4 steps).
// Grid: (kt=8, h=4, z=16); z<8: mono (b=z, +r, fp32 e_mono); z>=8: chunk
// (fp16 e_chunk16).
// ---------------------------------------------------------------------------
__global__ __launch_bounds__(256) void energy_mfma(
    const _Float16* __restrict__ Qm, const _Float16* __restrict__ Km,
    const _Float16* __restrict__ Qc, const _Float16* __restrict__ Kc,
    const int* __restrict__ mask, float* __restrict__ e_mono,
    _Float16* __restrict__ e_chunk16, const float* __restrict__ r_ptr)
{
    __shared__ _Float16 As[4096];
    __shared__ _Float16 Bs[4096];
    const int tid = threadIdx.x;
    const int lane = tid & 63, wave = tid >> 6;
    const int wm = wave >> 1, wn = wave & 1;
    const int col = lane & 15, quad = lane >> 4;
    const int kt0 = blockIdx.x * 128;
    const int h = blockIdx.y;
    const int z = blockIdx.z;
    const int b = z & 7;
    const bool mono = z < 8;
    const _Float16* Qp = mono ? Qm : Qc;
    const _Float16* Kp = mono ? Km : Kc;
    const float rv = mono ? r_ptr[0] : 0.f;

    f32x4 acc[4][4];
#pragma unroll
    for (int mt = 0; mt < 4; ++mt)
#pragma unroll
        for (int nt = 0; nt < 4; ++nt) acc[mt][nt] = (f32x4)0.f;
    gemm_acc_f16<4>(Qp + (size_t)(b * 128) * 512 + h * 128,
                    Kp + (size_t)(b * 1024 + kt0) * 512 + h * 128, As, Bs, acc);

#pragma unroll
    for (int mt = 0; mt < 4; ++mt) {
        const int qb = wm * 64 + mt * 16 + quad * 4;
#pragma unroll
        for (int nt = 0; nt < 4; ++nt) {
            const int kc = kt0 + wn * 64 + nt * 16 + col;
#pragma unroll
            for (int r = 0; r < 4; ++r) {
                const int q = qb + r;
                float v = acc[mt][nt][r] * INV_SCALE + rv;
                int mv = mask[((size_t)b * 128 + q) * 1024 + kc];
                v = mv ? v : NEG_INF;
                const size_t oi = (((size_t)b * 4 + h) * 128 + q) * 1024 + kc;
                if (mono) e_mono[oi] = v;
                else      e_chunk16[oi] = (_Float16)v;
            }
        }
    }
}

// ---------------------------------------------------------------------------
// transcend_row: (pcp, invcp) for one (b,h,q) row computed by one wave.
// ---------------------------------------------------------------------------
__device__ __forceinline__ void transcend_row(
    const float* __restrict__ Erow, int lane, float o_pcp[16], float o_inv[16])
{
    const float* E = Erow + lane * 16;
    float e[16];
    *(float4*)&e[0]  = *(const float4*)(E);
    *(float4*)&e[4]  = *(const float4*)(E + 4);
    *(float4*)&e[8]  = *(const float4*)(E + 8);
    *(float4*)&e[12] = *(const float4*)(E + 12);

    float p[16], l[16];
#pragma unroll
    for (int i = 0; i < 16; ++i) {
        p[i] = 1.f / (1.f + expf(-e[i]));
        l[i] = logf(fmaxf(1.f - p[i], EPS_MOCHA));
    }
    float incl[16];
    incl[0] = l[0];
#pragma unroll
    for (int i = 1; i < 16; ++i) incl[i] = incl[i - 1] + l[i];
    float total = incl[15];
    float x = wave_incl_scan(total);
    float base = x - total;  // exclusive across lanes
#pragma unroll
    for (int i = 0; i < 16; ++i) {
        float cl = base + (i ? incl[i - 1] : 0.f);
        float cp = expf(cl);
        o_pcp[i] = p[i] * cp;
        o_inv[i] = 1.f / fmaxf(cp, EPS_MOCHA);
    }
}

// ---------------------------------------------------------------------------
// alpha_pre: per row q (one wave, 4096 rows): pcp_q (stored) and
// G_q = pcp_{q-1} * invcp_q (G_0 = delta(k==0) * invcp_0[0]).
// ---------------------------------------------------------------------------
__global__ __launch_bounds__(256) void alpha_pre(
    const float* __restrict__ e_mono, float* __restrict__ G,
    float* __restrict__ pcp)
{
    const int tid = threadIdx.x;
    const int lane = tid & 63;
    const int row = blockIdx.x * 4 + (tid >> 6);
    const int q = row & 127;

    float pq[16], iq[16];
    transcend_row(e_mono + (size_t)row * 1024, lane, pq, iq);

    float* P = pcp + (size_t)row * 1024 + lane * 16;
    *(float4*)(P)      = *(float4*)&pq[0];
    *(float4*)(P + 4)  = *(float4*)&pq[4];
    *(float4*)(P + 8)  = *(float4*)&pq[8];
    *(float4*)(P + 12) = *(float4*)&pq[12];

    float g[16];
    if (q == 0) {
#pragma unroll
        for (int i = 0; i < 16; ++i) g[i] = 0.f;
        if (lane == 0) g[0] = iq[0];
    } else {
        float pm[16], im[16];
        transcend_row(e_mono + (size_t)(row - 1) * 1024, lane, pm, im);
#pragma unroll
        for (int i = 0; i < 16; ++i) g[i] = pm[i] * iq[i];
    }
    float* Gp = G + (size_t)row * 1024 + lane * 16;
    *(float4*)(Gp)      = *(float4*)&g[0];
    *(float4*)(Gp + 4)  = *(float4*)&g[4];
    *(float4*)(Gp + 8)  = *(float4*)&g[8];
    *(float4*)(Gp + 12) = *(float4*)&g[12];
}

// ---------------------------------------------------------------------------
// alpha_scan: one wave per (b,h), single 16MB stream (G), 8-deep prefetch,
// DPP wave scan. S_q = cumsum_k(G_q * S_{q-1}), S_{-1} = 1.
// ---------------------------------------------------------------------------
__global__ __launch_bounds__(64, 1) void alpha_scan(
    const float* __restrict__ G, float* __restrict__ S)
{
    const int lane = threadIdx.x;
    const int bh = blockIdx.x;
    const float* Gp = G + (size_t)bh * 131072 + lane * 16;
    float* Sp = S + (size_t)bh * 131072 + lane * 16;

    float bg[8][16];
#pragma unroll
    for (int s = 0; s < 8; ++s) {
        const float* Gq = Gp + (size_t)s * 1024;
        *(float4*)&bg[s][0]  = *(const float4*)(Gq);
        *(float4*)&bg[s][4]  = *(const float4*)(Gq + 4);
        *(float4*)&bg[s][8]  = *(const float4*)(Gq + 8);
        *(float4*)&bg[s][12] = *(const float4*)(Gq + 12);
    }

    float Sv[16];
#pragma unroll
    for (int i = 0; i < 16; ++i) Sv[i] = 1.f;  // S_{-1} = ones

    for (int q8 = 0; q8 < 128; q8 += 8) {
#pragma unroll
        for (int s = 0; s < 8; ++s) {
            const int q = q8 + s;
            float g[16];
#pragma unroll
            for (int i = 0; i < 16; ++i) g[i] = bg[s][i];
            if (q + 8 < 128) {  // refill slot s for q+8
                const float* Gq = Gp + (size_t)(q + 8) * 1024;
                *(float4*)&bg[s][0]  = *(const float4*)(Gq);
                *(float4*)&bg[s][4]  = *(const float4*)(Gq + 4);
                *(float4*)&bg[s][8]  = *(const float4*)(Gq + 8);
                *(float4*)&bg[s][12] = *(const float4*)(Gq + 12);
            }

            float incl[16];
            incl[0] = g[0] * Sv[0];
#pragma unroll
            for (int i = 1; i < 16; ++i)
                incl[i] = fmaf(g[i], Sv[i], incl[i - 1]);
            float total = incl[15];
            float x = wave_incl_scan(total);
            float base = x - total;
#pragma unroll
            for (int i = 0; i < 16; ++i) Sv[i] = base + incl[i];

            float* Sq = Sp + (size_t)q * 1024;
            *(float4*)(Sq)      = *(float4*)&Sv[0];
            *(float4*)(Sq + 4)  = *(float4*)&Sv[4];
            *(float4*)(Sq + 8)  = *(float4*)&Sv[8];
            *(float4*)(Sq + 12) = *(float4*)&Sv[12];
        }
    }
}

// ---------------------------------------------------------------------------
// Beta -> fp16. One block per (b,q); alpha = pcp*S reconstructed on load;
// e_chunk read as fp16. LDS swizzle SW(k)=k+(k>>3). Grid: (q=128, b=8).
// ---------------------------------------------------------------------------
#define SW(k) ((k) + ((k) >> 3))

__global__ __launch_bounds__(256) void beta_kernel(
    const _Float16* __restrict__ e_chunk16, const float* __restrict__ pcp,
    const float* __restrict__ S, _Float16* __restrict__ beta)
{
    __shared__ float sm[SW(1023) + 1];
    __shared__ float tm[SW(1027) + 1];
    __shared__ float red[4];
    const int q = blockIdx.x, b = blockIdx.y;
    const int tid = threadIdx.x;
    const int lane = tid & 63, wid = tid >> 6;
    const int k4 = tid * 4;

    float av[4][4];
#pragma unroll
    for (int hm = 0; hm < 4; ++hm) {
        const size_t off = (((size_t)b * 4 + hm) * 128 + q) * 1024 + k4;
        float4 pv = *(const float4*)(pcp + off);
        float4 sv = *(const float4*)(S + off);
        av[hm][0] = pv.x * sv.x;
        av[hm][1] = pv.y * sv.y;
        av[hm][2] = pv.z * sv.z;
        av[hm][3] = pv.w * sv.w;
    }

    if (tid < 4) tm[SW(1024 + tid)] = 0.f;  // fwd-window zero pad (set once)

    for (int hc = 0; hc < 4; ++hc) {
        half4v ev = *(const half4v*)(e_chunk16 + (((size_t)b * 4 + hc) * 128 + q) * 1024 + k4);
        float e[4] = {(float)ev[0], (float)ev[1], (float)ev[2], (float)ev[3]};

        float mx = fmaxf(fmaxf(e[0], e[1]), fmaxf(e[2], e[3]));
#pragma unroll
        for (int off = 32; off >= 1; off >>= 1)
            mx = fmaxf(mx, __shfl_xor(mx, off, 64));
        if (lane == 0) red[wid] = mx;
        __syncthreads();
        mx = fmaxf(fmaxf(red[0], red[1]), fmaxf(red[2], red[3]));

        float sx[4];
#pragma unroll
        for (int i = 0; i < 4; ++i) {
            sx[i] = fmaxf(expf(e[i] - mx), 1e-5f);
            sm[SW(k4 + i)] = sx[i];
        }
        __syncthreads();

        float den[4];
#pragma unroll
        for (int i = 0; i < 4; ++i) {
            int k = k4 + i;
            float d = sm[SW(k)];
            if (k >= 1) d += sm[SW(k - 1)];
            if (k >= 2) d += sm[SW(k - 2)];
            if (k >= 3) d += sm[SW(k - 3)];
            den[i] = d;
        }

#pragma unroll
        for (int hm = 0; hm < 4; ++hm) {
            float t[4] = {av[hm][0] / den[0], av[hm][1] / den[1],
                          av[hm][2] / den[2], av[hm][3] / den[3]};
#pragma unroll
            for (int i = 0; i < 4; ++i) tm[SW(k4 + i)] = t[i];
            __syncthreads();
            float o[4];
#pragma unroll
            for (int i = 0; i < 4; ++i) {
                int k = k4 + i;
                float ms = tm[SW(k)] + tm[SW(k + 1)] + tm[SW(k + 2)] + tm[SW(k + 3)];
                o[i] = sx[i] * ms;
            }
            _Float16* Brow = beta + (((size_t)b * 16 + hm * 4 + hc) * 128 + q) * 1024;
            half4v hv = {(_Float16)o[0], (_Float16)o[1], (_Float16)o[2], (_Float16)o[3]};
            *(half4v*)(Brow + k4) = hv;
            __syncthreads();
        }
    }
}

// ---------------------------------------------------------------------------
// Context: cv16[b,q,h*32+d] = (fp16) sum_k beta16[b,h,q,k] * V[b,k,h*32+d]
// ---------------------------------------------------------------------------
__global__ __launch_bounds__(256) void context_kernel(
    const _Float16* __restrict__ beta, const float* __restrict__ V,
    _Float16* __restrict__ cv16)
{
    __shared__ float bS[32][64];
    __shared__ float vS[32][32];
    const int qh = blockIdx.x, h = blockIdx.y, b = blockIdx.z;
    const int tid = threadIdx.x;
    const int ty = tid >> 3, tx = tid & 7;
    const int q0 = qh * 64;

    const _Float16* Bbase = beta + (((size_t)b * 16 + h) * 128 + q0) * 1024;
    const float* Vbase = V + (size_t)b * 1024 * 512 + h * 32;

    float acc[2][4];
#pragma unroll
    for (int i = 0; i < 2; ++i)
#pragma unroll
        for (int j = 0; j < 4; ++j) acc[i][j] = 0.f;

    for (int k0 = 0; k0 < 1024; k0 += 32) {
        {
            int r = tid >> 2, c = tid & 3;
            half8 v = *(const half8*)(Bbase + (size_t)r * 1024 + k0 + c * 8);
#pragma unroll
            for (int j = 0; j < 8; ++j) bS[c * 8 + j][r] = (float)v[j];
        }
        {
            int kk = tid >> 3, c = tid & 7;
            float4 v = *(const float4*)(Vbase + (size_t)(k0 + kk) * 512 + c * 4);
            *(float4*)&vS[kk][c * 4] = v;
        }
        __syncthreads();
#pragma unroll
        for (int kk = 0; kk < 32; ++kk) {
            float a0 = bS[kk][ty * 2], a1 = bS[kk][ty * 2 + 1];
            float bb[4];
            *(float4*)bb = *(const float4*)&vS[kk][tx * 4];
#pragma unroll
            for (int j = 0; j < 4; ++j) {
                acc[0][j] = fmaf(a0, bb[j], acc[0][j]);
                acc[1][j] = fmaf(a1, bb[j], acc[1][j]);
            }
        }
        __syncthreads();
    }
#pragma unroll
    for (int i = 0; i < 2; ++i) {
        _Float16* Cp = cv16 + ((size_t)b * 128 + q0 + ty * 2 + i) * 512 + h * 32 + tx * 4;
        half4v hv = {(_Float16)acc[i][0], (_Float16)acc[i][1],
                     (_Float16)acc[i][2], (_Float16)acc[i][3]};
        *(half4v*)Cp = hv;
    }
}

// ---------------------------------------------------------------------------
extern "C" void kernel_launch(void* const* d_in, const int* in_sizes, int n_in,
                              void* d_out, int out_size, void* d_ws, size_t ws_size,
                              hipStream_t stream)
{
    const float* key_x   = (const float*)d_in[0];
    const float* query_x = (const float*)d_in[1];
    const int*   mask    = (const int*)d_in[2];
    const float* wk_m = (const float*)d_in[3];
    const float* bk_m = (const float*)d_in[4];
    const float* wq_m = (const float*)d_in[5];
    const float* bq_m = (const float*)d_in[6];
    const float* r    = (const float*)d_in[7];
    const float* wk_c = (const float*)d_in[8];
    const float* bk_c = (const float*)d_in[9];
    const float* wq_c = (const float*)d_in[10];
    const float* bq_c = (const float*)d_in[11];
    const float* wv   = (const float*)d_in[12];
    const float* bv   = (const float*)d_in[13];
    const float* wo   = (const float*)d_in[14];
    const float* bo   = (const float*)d_in[15];
    float* out = (float*)d_out;

    float* ws = (float*)d_ws;
    _Float16* hws = (_Float16*)d_ws;
    const size_t MEGF = 1024 * 1024;
    // Float-unit layout (fp16 offsets are 2x float offsets), lifetime-audited:
    //  phase A (prep_weights, proj5, energy):
    //    Km16 f[0,2), Kc16 f[2,4), Qm16 f[4,4.25), Qc16 f[4.25,4.5),
    //    e_mono f[11,15), e_chunk16 f[17,19), V f[19,23),
    //    Wt5 f[27,27.625), Wt_wo f[27.625,27.75)  [survive to proj_out]
    //  phase B (alpha): G f[0,4) (over dead Km/Kc), pcp f[4,8) (over dead
    //    Qm/Qc + free) — NO overlap with e_mono f[11,15) (R13/14 race fixed);
    //    S f[23,27)
    //  phase C (beta/context): beta16 f[8,16) (over free f[8,11) + dead
    //    e_mono), cv16 f[27.75,28). Peak 28 MEGF.
    _Float16* Km16  = hws;                          // f 0
    _Float16* Kc16  = hws + 4 * MEGF;               // f 2
    _Float16* Qm16  = hws + 8 * MEGF;               // f 4
    _Float16* Qc16  = hws + 8 * MEGF + 524288;      // f 4.25
    float* e_mono  = ws + 11 * MEGF;
    _Float16* e_chunk16 = hws + 34 * MEGF;          // f 17
    float* V       = ws + 19 * MEGF;
    float* G       = ws;                            // f 0
    float* pcp     = ws + 4 * MEGF;                 // f 4
    float* S       = ws + 23 * MEGF;                // f 23
    _Float16* beta16 = hws + 16 * MEGF;             // f 8
    _Float16* Wt5   = hws + 54 * MEGF;              // f 27
    _Float16* Wt_wo = hws + 54 * MEGF + 5 * 262144; // f 27.625
    _Float16* cv16  = hws + 55 * MEGF + MEGF / 2;   // f 27.75

    // 0) weight packing only (activation cvt fused into proj5)
    prep_weights<<<dim3(8, 8, 6), 256, 0, stream>>>(
        wk_m, wk_c, wv, wq_m, wq_c, wo, Wt5, Wt_wo);
    // 1) all five projections in one launch (A = fp32, cvt in staging)
    mfma_proj5<<<dim3(64, 20), 256, 0, stream>>>(
        key_x, query_x, Wt5,
        bk_m, Km16, bk_c, Kc16, bv, V, bq_m, Qm16, bq_c, Qc16);
    // 2) both energies in one launch (chunk head -> fp16)
    energy_mfma<<<dim3(8, 4, 16), 256, 0, stream>>>(
        Qm16, Km16, Qc16, Kc16, mask, e_mono, e_chunk16, r);
    // 3) monotonic alpha: G/pcp precompute + single-stream DPP scan
    alpha_pre<<<dim3(1024), 256, 0, stream>>>(e_mono, G, pcp);
    alpha_scan<<<dim3(32), 64, 0, stream>>>(G, S);
    // 4) chunkwise beta (fp16 out), one block per (b,q); aw = pcp*S inline
    beta_kernel<<<dim3(128, 8), 256, 0, stream>>>(e_chunk16, pcp, S, beta16);
    // 5) context vectors -> cv16 directly
    context_kernel<<<dim3(2, 16, 8), 256, 0, stream>>>(beta16, V, cv16);
    // 6) output projection (M=1024, fp32 out)
    mfma_proj_out<<<dim3(8, 4), 256, 0, stream>>>(cv16, Wt_wo, bo, out);
}